// Round 1
// baseline (83.013 us; speedup 1.0000x reference)
//
#include <hip/hip_runtime.h>
#include <math.h>

// HorizonReward: 60-step UT cartpole rollout, single wave, zero LDS.
//
// v2 restructure: single-round reductions.
// The center sigma point has zero offset -> its dynamics are wave-uniform and
// depend only on the mean state (NOT on the fresh Cholesky). Working with
// deviations from the center value (delta = f_point - f_center) and expanding
// the u-affine deltas as polynomials in u gives
//     cov5 = sum(0.5*delta*delta^T) - 5*mu_d*mu_d^T,   mu_d = 0.1*sum(delta)
// so ALL 27 sums (6 means + 21 Gram entries) reduce in ONE pre-u round.
// Sigma points are packed in 8 lanes -> 8 reduction rows of 8 lanes each,
// 3 DPP stages per reduction (quad_perm,quad_perm,row_half_mirror) instead of
// the previous two serial 4-stage rounds (one of which was gated on u).
// mu_d is second-order small (symmetric +/- points), so the -5*mu*mu
// correction causes no cancellation. Cholesky / policy / f64 angle
// accumulator are unchanged from the verified v1.

template <int CTRL>
__device__ __forceinline__ float dpp_add_f(float v) {
    int s = __builtin_amdgcn_update_dpp(0, __float_as_int(v), CTRL, 0xF, 0xF, true);
    return v + __int_as_float(s);
}
// sum within each 16-lane row (policy reduction only)
__device__ __forceinline__ float row_sum_f(float v) {
    v = dpp_add_f<0xB1>(v);
    v = dpp_add_f<0x4E>(v);
    v = dpp_add_f<0x124>(v);
    v = dpp_add_f<0x128>(v);
    return v;
}
// sum within each 8-lane group: quad_perm[1,0,3,2], quad_perm[2,3,0,1],
// row_half_mirror. All 8 lanes of the group end with the group sum.
__device__ __forceinline__ float row_sum8_f(float v) {
    v = dpp_add_f<0xB1>(v);
    v = dpp_add_f<0x4E>(v);
    v = dpp_add_f<0x141>(v);
    return v;
}
__device__ __forceinline__ float rl(float v, int lane) {
    return __int_as_float(__builtin_amdgcn_readlane(__float_as_int(v), lane));
}
// full 64-lane sum -> lane63, via row_bcast15 / row_bcast31
__device__ __forceinline__ float wave_sum_f(float v) {
    v = row_sum_f(v);
    v = dpp_add_f<0x142>(v);
    v = dpp_add_f<0x143>(v);
    return rl(v, 63);
}

__global__ __launch_bounds__(64) void horizon_kernel(const float* __restrict__ p,
                                                     float* __restrict__ out) {
    const int l = threadIdx.x;
    const int k = l & 7;    // sigma slot: 0..7 = the eight +/- points
    const int r = l >> 3;   // reduction row 0..7

    const float SQL2E  = 1.2011224087864498f;   // sqrt(log2 e)
    const float INV_MT = 0.9090909090909091f;   // 1/1.1
    const float KCS    = -0.045454545454545456f;// -0.05/1.1
    const double INV2PI_D = 0.15915494309189535;
    const float  INV2PI_F = 0.15915494309189535f;
    const float DIAG5  = 0.00251f;              // 5*(PN*DT + 2*JITTER)

    // per-lane RBF params, s pre-scaled so exp(-qn) = exp2(-(qn*log2e))
    float w = 0.0f, mu0 = 0.0f, mu1 = 0.0f, mu2 = 0.0f, mu3 = 0.0f;
    float s0=0,s1=0,s2=0,s3=0,s4=0,s5=0,s6=0,s7=0,s8=0,s9=0;
    if (l < 50) {
        w   = p[l];
        mu0 = p[ 50 + l]; mu1 = p[100 + l]; mu2 = p[150 + l]; mu3 = p[200 + l];
        const float* q = p + 250 + 10 * l;
        s0 = q[0]*SQL2E; s1 = q[1]*SQL2E; s2 = q[2]*SQL2E; s3 = q[3]*SQL2E;
        s4 = q[4]*SQL2E; s5 = q[5]*SQL2E; s6 = q[6]*SQL2E; s7 = q[7]*SQL2E;
        s8 = q[8]*SQL2E; s9 = q[9]*SQL2E;
    }

    // sigma role: points 1..4 = +columns, 5..8 = -columns
    const float osgn = (k < 4) ? 1.0f : -1.0f;
    const int   ocol = k & 3;

    // loop-invariant row-select masks (hoisted v_cmp -> sgpr masks)
    const bool rb0  = (r & 1) != 0;
    const bool rb1v = (r & 2) != 0;
    const bool rb2v = (r & 4) != 0;
    const bool hi67 = (r >= 6);
    const bool lt5  = (r < 5);
    const bool r7q  = (r == 7);
    const bool r0q  = (r == 0);
    const bool r2q  = (r == 2);
    const bool rle2 = (r <= 2);

    // carried state (all f32 except angle accumulator rev)
    float mmf0 = 0.0f, mmf1 = 0.0f, mmf2 = 0.1f, mmf3 = 0.0f;
    float d0 = -mu0, d1 = -mu1, d2 = 0.1f - mu2, d3 = -mu3;
    double rev = 0.1 * INV2PI_D;                // theta / 2pi, kept in [0,1)
    float frmf = (float)rev;
    const float CI = 2.2360679774997896e-3f;    // sqrt5 * chol(JITTER*I)
    float c00=CI, c10=0.f, c20=0.f, c30=0.f;
    float c11=CI, c21=0.f, c31=0.f;
    float c22=CI, c32=0.f;
    float c33=CI;
    float acc = 0.0f;

    #pragma unroll 2
    for (int t = 0; t < 60; ++t) {
        // ===== center dynamics (wave-uniform; independent of the Cholesky) =====
        float snc = __builtin_amdgcn_sinf(frmf);
        float csc = __builtin_amdgcn_cosf(frmf);
        float a_c  = (0.045454545454545456f * (mmf3 * mmf3)) * snc;
        float denc = fmaf(csc * csc, KCS, 0.6666666666666666f);
        float rdc  = __builtin_amdgcn_rcpf(denc);
        float g0c = fmaf(9.8f, snc, -(csc * a_c)) * rdc;
        float g1c = (-INV_MT) * (csc * rdc);
        float kcsc = KCS * csc;
        float h0c = fmaf(kcsc, g0c, a_c);
        float h1c = fmaf(kcsc, g1c, INV_MT);
        float fac = 0.05f * mmf1;   // dl0 at center
        float fbc = 0.05f * h0c;    // al1 at center
        float fcc = 0.05f * h1c;    // be1 at center
        float fdc = 0.05f * mmf3;   // dl2 at center
        float fec = 0.05f * g0c;    // al3 at center
        float ffc = 0.05f * g1c;    // be3 at center

        // ===== per-lane sigma offsets & dynamics (needs Cholesky) =====
        float oo0 = osgn * ((ocol == 0) ? c00 : 0.0f);
        float oo1 = osgn * ((ocol == 0) ? c10 : ((ocol == 1) ? c11 : 0.0f));
        float oo2 = osgn * ((ocol == 0) ? c20 : ((ocol == 1) ? c21 :
                            ((ocol == 2) ? c22 : 0.0f)));
        float oo3 = osgn * ((ocol == 0) ? c30 : ((ocol == 1) ? c31 :
                            ((ocol == 2) ? c32 : c33)));

        float x1 = mmf1 + oo1;
        float x3 = mmf3 + oo3;
        float rv = __builtin_amdgcn_fractf(fmaf(oo2, INV2PI_F, frmf));
        float sn = __builtin_amdgcn_sinf(rv);
        float cs = __builtin_amdgcn_cosf(rv);
        float a   = (0.045454545454545456f * (x3 * x3)) * sn;
        float den = fmaf(cs * cs, KCS, 0.6666666666666666f);
        float rden = __builtin_amdgcn_rcpf(den);
        float g0 = fmaf(9.8f, sn, -(cs * a)) * rden;
        float g1 = (-INV_MT) * (cs * rden);
        float kcs = KCS * cs;
        float h0 = fmaf(kcs, g0, a);
        float h1 = fmaf(kcs, g1, INV_MT);
        float fa = fmaf(0.05f, x1, oo0);   // A: dl0  (u-free)
        float fb = fmaf(0.05f, h0, oo1);   // B: al1  (dl1 = al1 + be1*u)
        float fc_ = 0.05f * h1;            // C: be1
        float fd = fmaf(0.05f, x3, oo2);   // D: dl2  (u-free)
        float fe = fmaf(0.05f, g0, oo3);   // E: al3  (dl3 = al3 + be3*u)
        float ff_ = 0.05f * g1;            // F: be3

        // ===== policy (uses d from previous step; large slack vs chain) =====
        float t0p = fmaf(s0, d0, s5 * d2);
        float t1p = s6 * d2;
        float t2p = s2 * d2;
        float t0v = fmaf(s4, d1, fmaf(s7, d3, t0p));
        float t1v = fmaf(s1, d1, fmaf(s8, d3, t1p));
        float t2v = fmaf(s9, d3, t2p);
        float t3v = s3 * d3;
        float qn = fmaf(t0v, t0v, fmaf(t1v, t1v, fmaf(t2v, t2v, t3v * t3v)));
        float val = wave_sum_f(w * __builtin_amdgcn_exp2f(-qn));
        float u = fminf(10.0f, fmaxf(-10.0f, val));

        // ===== deltas from center (center contributes 0 to every sum) =====
        float da = fa - fac, db = fb - fbc, dc_ = fc_ - fcc;
        float dd = fd - fdc, de = fe - fec, df_ = ff_ - ffc;
        float ha = 0.5f * da, hb = 0.5f * db, hc = 0.5f * dc_;
        float hd = 0.5f * dd, he = 0.5f * de, hf = 0.5f * df_;

        // ===== single reduction round: 4 calls x 8 row-specialized slots =====
        // call1 rows 0..7: AA AB AC AD AE AF | mean(A) mean(B)
        float c1a = rb0 ? hb : ha;
        float c1b = rb0 ? hd : hc;
        float c1c = rb0 ? hf : he;
        float c1m0 = rb1v ? c1b : c1a;
        float c1m1 = rb1v ? c1a : c1c;     // rows 6,7 reuse (A,B)
        float xs1 = rb2v ? c1m1 : c1m0;
        float ys1 = hi67 ? 1.0f : da;
        float sr1 = row_sum8_f(xs1 * ys1);

        // call2 rows 0..7: BB BC BD BE BF | mean(C) mean(D) mean(E)
        float c2a = rb0 ? hc : hb;
        float c2b = rb0 ? he : hd;
        float c2c = rb0 ? hc : hf;
        float c2m0 = rb1v ? c2b : c2a;
        float c2m1 = rb1v ? c2b : c2c;
        float xs2 = rb2v ? c2m1 : c2m0;
        float ys2 = lt5 ? db : 1.0f;
        float sr2 = row_sum8_f(xs2 * ys2);

        // call3 rows 0..7: CC CD CE CF DD DE DF | mean(F)
        float c3a = rb0 ? hd : hc;
        float c3b = rb0 ? hf : he;
        float c3c = rb0 ? he : hd;
        float c3m0 = rb1v ? c3b : c3a;
        float c3m1 = rb1v ? hf  : c3c;
        float xs3 = rb2v ? c3m1 : c3m0;
        float ys3 = rb2v ? (r7q ? 1.0f : dd) : dc_;
        float sr3 = row_sum8_f(xs3 * ys3);

        // call4 rows 0..2: EE EF FF (rows 3..7 contribute 0)
        float xs4 = r2q ? hf : he;
        float ys4 = r0q ? de : (rle2 ? df_ : 0.0f);
        float sr4 = row_sum8_f(xs4 * ys4);

        // broadcast all 27 sums (uniform scalars)
        float SAA = rl(sr1,  0), SAB = rl(sr1,  8), SAC = rl(sr1, 16);
        float SAD = rl(sr1, 24), SAE = rl(sr1, 32), SAF = rl(sr1, 40);
        float SmA = rl(sr1, 48), SmB = rl(sr1, 56);
        float SBB = rl(sr2,  0), SBC = rl(sr2,  8), SBD = rl(sr2, 16);
        float SBE = rl(sr2, 24), SBF = rl(sr2, 32);
        float SmC = rl(sr2, 40), SmD = rl(sr2, 48), SmE = rl(sr2, 56);
        float SCC = rl(sr3,  0), SCD = rl(sr3,  8), SCE = rl(sr3, 16);
        float SCF = rl(sr3, 24), SDD = rl(sr3, 32), SDE = rl(sr3, 40);
        float SDF = rl(sr3, 48), SmF = rl(sr3, 56);
        float SEE = rl(sr4,  0), SEF = rl(sr4,  8), SFF = rl(sr4, 16);

        // means: mu_x = 0.1*sum(delta_x) = 0.2*SmX;  A_x = center + mu_x
        float muA = 0.2f * SmA, muB = 0.2f * SmB, muC = 0.2f * SmC;
        float muD = 0.2f * SmD, muE = 0.2f * SmE, muF = 0.2f * SmF;
        float A0 = fac + muA;
        float A1 = fbc + muB;
        float B1 = fcc + muC;
        float A2 = fdc + muD;
        float A3 = fec + muE;
        float B3 = ffc + muF;

        // cov5 Gram coefficients: C_xy = S_xy - 5*mu_x*mu_y = S_xy - SmX*mu_y
        float CAA = fmaf(-SmA, muA, SAA);
        float CAB = fmaf(-SmA, muB, SAB);
        float CAC = fmaf(-SmA, muC, SAC);
        float CAD = fmaf(-SmA, muD, SAD);
        float CAE = fmaf(-SmA, muE, SAE);
        float CAF = fmaf(-SmA, muF, SAF);
        float CBB = fmaf(-SmB, muB, SBB);
        float CBC = fmaf(-SmB, muC, SBC);
        float CBD = fmaf(-SmB, muD, SBD);
        float CBE = fmaf(-SmB, muE, SBE);
        float CBF = fmaf(-SmB, muF, SBF);
        float CCC = fmaf(-SmC, muC, SCC);
        float CCD = fmaf(-SmC, muD, SCD);
        float CCE = fmaf(-SmC, muE, SCE);
        float CCF = fmaf(-SmC, muF, SCF);
        float CDD = fmaf(-SmD, muD, SDD);
        float CDE = fmaf(-SmD, muE, SDE);
        float CDF = fmaf(-SmD, muF, SDF);
        float CEE = fmaf(-SmE, muE, SEE);
        float CEF = fmaf(-SmE, muF, SEF);
        float CFF = fmaf(-SmF, muF, SFF);

        // covariance entries as short Horner polynomials in u
        float E00 = CAA + DIAG5;
        float E10 = fmaf(CAC, u, CAB);
        float E11 = fmaf(fmaf(CCC, u, CBC + CBC), u, CBB) + DIAG5;
        float E20 = CAD;
        float E21 = fmaf(CCD, u, CBD);
        float E22 = CDD + DIAG5;
        float E30 = fmaf(CAF, u, CAE);
        float E31 = fmaf(fmaf(CCF, u, CBF + CCE), u, CBE);
        float E32 = fmaf(CDF, u, CDE);
        float E33 = fmaf(fmaf(CFF, u, CEF + CEF), u, CEE) + DIAG5;

        // state / policy-input updates
        float rd1 = fmaf(B1, u, A1);
        float rd3 = fmaf(B3, u, A3);
        d0 += A0; d2 += A2; d1 += rd1; d3 += rd3;
        float nmm0 = mmf0 + A0, nmm1 = mmf1 + rd1;
        float nmm2 = mmf2 + A2, nmm3 = mmf3 + rd3;
        double revn = fma((double)A2, INV2PI_D, rev);
        rev = revn - floor(revn);
        float nfrm = (float)rev;

        // reward (post-step mean & cov)
        float rwm = fmaf(nmm0, nmm0, fmaf(nmm1, nmm1,
                    fmaf(10.0f * nmm2, nmm2, nmm3 * nmm3)));
        float rwa = E00 + E11 + 10.0f * E22 + E33;
        acc -= fmaf(0.2f, rwa, rwm);

        // Cholesky of 5*cov (unchanged structure)
        float i0 = __builtin_amdgcn_rsqf(E00);
        float nc00 = E00 * i0;
        float nc10 = E10 * i0;
        float nc20 = E20 * i0;
        float nc30 = E30 * i0;
        float b11 = fmaf(-nc10, nc10, E11);
        float i1 = __builtin_amdgcn_rsqf(b11);
        float nc11 = b11 * i1;
        float nc21 = fmaf(-nc20, nc10, E21) * i1;
        float nc31 = fmaf(-nc30, nc10, E31) * i1;
        float b22 = fmaf(-nc21, nc21, fmaf(-nc20, nc20, E22));
        float i2 = __builtin_amdgcn_rsqf(b22);
        float nc22 = b22 * i2;
        float nc32 = fmaf(-nc31, nc21, fmaf(-nc30, nc20, E32)) * i2;
        float b33 = fmaf(-nc32, nc32, fmaf(-nc31, nc31, fmaf(-nc30, nc30, E33)));
        float nc33 = b33 * __builtin_amdgcn_rsqf(b33);

        c00 = nc00; c10 = nc10; c20 = nc20; c30 = nc30;
        c11 = nc11; c21 = nc21; c31 = nc31;
        c22 = nc22; c32 = nc32; c33 = nc33;
        mmf0 = nmm0; mmf1 = nmm1; mmf2 = nmm2; mmf3 = nmm3;
        frmf = nfrm;
    }

    if (l == 0) out[0] = acc;
}

extern "C" void kernel_launch(void* const* d_in, const int* in_sizes, int n_in,
                              void* d_out, int out_size, void* d_ws, size_t ws_size,
                              hipStream_t stream) {
    (void)in_sizes; (void)n_in; (void)out_size; (void)d_ws; (void)ws_size;
    const float* p = (const float*)d_in[0];
    float* out = (float*)d_out;
    hipLaunchKernelGGL(horizon_kernel, dim3(1), dim3(64), 0, stream, p, out);
}

// Round 2
// 73.536 us; speedup vs baseline: 1.1289x; 1.1289x over previous
//
#include <hip/hip_runtime.h>
#include <math.h>

// HorizonReward: 60-step UT cartpole rollout, single wave, zero LDS.
//
// v3 = v1 structure (proven 74 µs) + two surgical cuts, informed by v2's
// post-mortem (issue-bound: added instructions convert ~1:1 into cycles):
//  (a) pre-u second moments via raw-moment identity  5*cov = S - 5*mu*mu:
//      PB rows now carry {5w*dl0^2, w*be1, 5w*dl0*dl2, w*be3}, reduced IN
//      PARALLEL with PA (v1's P1 round had to wait on PA's readlanes).
//      3 fma corrections after the readlanes. v2 validated the identity
//      numerically (absmax stayed 0.0 with it applied everywhere).
//  (b) the remaining second moment 5w*v2*v2 rides in P3's free row-3 slot
//      (operand ready pre-u; A22 is first consumed post-u at b22), deleting
//      one full reduction round: 5 rounds/iter -> 4.
// Everything else (policy, dynamics, f64 angle accumulator, Cholesky,
// row-replicated roles on (lane&15)) is byte-for-byte v1.

template <int CTRL>
__device__ __forceinline__ float dpp_add_f(float v) {
    int s = __builtin_amdgcn_update_dpp(0, __float_as_int(v), CTRL, 0xF, 0xF, true);
    return v + __int_as_float(s);
}
// sum within each 16-lane row: quad_perm[1,0,3,2], quad_perm[2,3,0,1],
// row_ror:4, row_ror:8
__device__ __forceinline__ float row_sum_f(float v) {
    v = dpp_add_f<0xB1>(v);
    v = dpp_add_f<0x4E>(v);
    v = dpp_add_f<0x124>(v);
    v = dpp_add_f<0x128>(v);
    return v;
}
__device__ __forceinline__ float rl(float v, int lane) {
    return __int_as_float(__builtin_amdgcn_readlane(__float_as_int(v), lane));
}
// full 64-lane sum -> lane63, via row_bcast15 / row_bcast31
__device__ __forceinline__ float wave_sum_f(float v) {
    v = row_sum_f(v);
    v = dpp_add_f<0x142>(v);
    v = dpp_add_f<0x143>(v);
    return rl(v, 63);
}

__global__ __launch_bounds__(64) void horizon_kernel(const float* __restrict__ p,
                                                     float* __restrict__ out) {
    const int l   = threadIdx.x;
    const int l15 = l & 15;
    const bool r1 = (l >> 4) & 1, r2 = (l >> 4) & 2;   // row bits

    const float SQL2E  = 1.2011224087864498f;   // sqrt(log2 e)
    const float INV_MT = 0.9090909090909091f;   // 1/1.1
    const float KCS    = -0.045454545454545456f;// -PML*LEN... = -0.05/1.1
    const double INV2PI_D = 0.15915494309189535;
    const float  INV2PI_F = 0.15915494309189535f;
    const float DIAG5  = 0.00251f;              // 5*(PN*DT + 2*JITTER)

    // per-lane RBF params, s pre-scaled so exp(-qn) = exp2(-(qn*log2e))
    float w = 0.0f, mu0 = 0.0f, mu1 = 0.0f, mu2 = 0.0f, mu3 = 0.0f;
    float s0=0,s1=0,s2=0,s3=0,s4=0,s5=0,s6=0,s7=0,s8=0,s9=0;
    if (l < 50) {
        w   = p[l];
        mu0 = p[ 50 + l]; mu1 = p[100 + l]; mu2 = p[150 + l]; mu3 = p[200 + l];
        const float* q = p + 250 + 10 * l;
        s0 = q[0]*SQL2E; s1 = q[1]*SQL2E; s2 = q[2]*SQL2E; s3 = q[3]*SQL2E;
        s4 = q[4]*SQL2E; s5 = q[5]*SQL2E; s6 = q[6]*SQL2E; s7 = q[7]*SQL2E;
        s8 = q[8]*SQL2E; s9 = q[9]*SQL2E;
    }

    // sigma-point role from (l&15)
    const float wlf  = (l15 == 0) ? 0.2f : ((l15 < 9) ? 0.1f : 0.0f);
    const float fw5  = 5.0f * wlf;
    const float osgn = (l15 >= 1 && l15 <= 4) ? 1.0f
                     : ((l15 >= 5 && l15 <= 8) ? -1.0f : 0.0f);
    const int   ocol = ((l15 >= 5 ? l15 - 5 : l15 - 1) & 3);

    // carried state (all f32 except angle accumulator rev)
    float mmf0 = 0.0f, mmf1 = 0.0f, mmf2 = 0.1f, mmf3 = 0.0f;
    float d0 = -mu0, d1 = -mu1, d2 = 0.1f - mu2, d3 = -mu3;
    double rev = 0.1 * INV2PI_D;                // theta / 2pi, kept in [0,1)
    float frmf = (float)rev;
    const float CI = 2.2360679774997896e-3f;    // sqrt5 * chol(JITTER*I)
    float c00=CI, c10=0.f, c20=0.f, c30=0.f;
    float c11=CI, c21=0.f, c31=0.f;
    float c22=CI, c32=0.f;
    float c33=CI;
    float acc = 0.0f;

    #pragma unroll 2
    for (int t = 0; t < 60; ++t) {
        // ================= pre-u phase =================
        // sigma offset for this lane (column ocol of sqrt5-scaled chol)
        float oo0 = osgn * ((ocol == 0) ? c00 : 0.0f);
        float oo1 = osgn * ((ocol == 0) ? c10 : ((ocol == 1) ? c11 : 0.0f));
        float oo2 = osgn * ((ocol == 0) ? c20 : ((ocol == 1) ? c21 :
                            ((ocol == 2) ? c22 : 0.0f)));
        float oo3 = osgn * ((ocol == 0) ? c30 : ((ocol == 1) ? c31 :
                            ((ocol == 2) ? c32 : c33)));

        float x1 = mmf1 + oo1;
        float x3 = mmf3 + oo3;

        // dynamics coefficients (affine in u): thacc=g0+g1u, xacc=h0+h1u
        float rv = __builtin_amdgcn_fractf(fmaf(oo2, INV2PI_F, frmf));
        float sn = __builtin_amdgcn_sinf(rv);
        float cs = __builtin_amdgcn_cosf(rv);
        float a   = (0.045454545454545456f * (x3 * x3)) * sn;  // temp - u/MT
        float den = fmaf(cs * cs, KCS, 0.6666666666666666f);
        float rden = __builtin_amdgcn_rcpf(den);
        float g0 = fmaf(9.8f, sn, -(cs * a)) * rden;
        float g1 = (-INV_MT) * (cs * rden);
        float kcs = KCS * cs;
        float h0 = fmaf(kcs, g0, a);
        float h1 = fmaf(kcs, g1, INV_MT);
        float al1 = fmaf(0.05f, h0, oo1), be1 = 0.05f * h1;   // dl1 = al1+be1*u
        float al3 = fmaf(0.05f, g0, oo3), be3 = 0.05f * g1;   // dl3 = al3+be3*u
        float dl0 = fmaf(0.05f, x1, oo0);                     // u-free
        float dl2 = fmaf(0.05f, x3, oo2);                     // u-free

        // mean sums, row-specialized: rows reduce {dl0, al1, dl2, al3}
        float selA = r1 ? (r2 ? al3 : al1) : (r2 ? dl2 : dl0);
        float PA = row_sum_f(wlf * selA);
        // raw second moments + u-coefficient means, IN PARALLEL with PA:
        // rows {5w*dl0*dl0, w*be1, 5w*dl0*dl2, w*be3}
        float fw5dl0 = fw5 * dl0;
        float xb = r1 ? (r2 ? be3 : be1) : (r2 ? dl2 : dl0);
        float yb = r1 ? wlf : fw5dl0;
        float PB = row_sum_f(xb * yb);

        float A0 = rl(PA, 0), A1 = rl(PA, 16), A2 = rl(PA, 32), A3 = rl(PA, 48);
        float S00 = rl(PB, 0), B1 = rl(PB, 16), S20 = rl(PB, 32), B3 = rl(PB, 48);

        // centered second moments via S - 5*mu*mu (validated in v2)
        float fA0 = 5.0f * A0;
        float A00 = fmaf(-fA0, A0, S00) + DIAG5;
        float A20 = fmaf(-fA0, A2, S20);
        float i0 = __builtin_amdgcn_rsqf(A00);
        float nc00 = A00 * i0;
        float nc20 = A20 * i0;

        // u-free centered pieces
        float v0 = dl0 - A0, v2 = dl2 - A2;
        float va1 = al1 - A1, vb1 = be1 - B1;
        float va3 = al3 - A3, vb3 = be3 - B3;

        // mean components 0,2 update pre-u (no u dependence)
        float nmm0 = mmf0 + A0, nmm2 = mmf2 + A2;
        double revn = fma((double)A2, INV2PI_D, rev);
        rev = revn - floor(revn);
        float nfrm = (float)rev;

        // ================= policy (uses current d) =================
        float t0p = fmaf(s0, d0, s5 * d2);
        float t1p = s6 * d2;
        float t2p = s2 * d2;
        float t0v = fmaf(s4, d1, fmaf(s7, d3, t0p));
        float t1v = fmaf(s1, d1, fmaf(s8, d3, t1p));
        float t2v = fmaf(s9, d3, t2p);
        float t3v = s3 * d3;
        float qn = fmaf(t0v, t0v, fmaf(t1v, t1v, fmaf(t2v, t2v, t3v * t3v)));
        float val = wave_sum_f(w * __builtin_amdgcn_exp2f(-qn));
        float u = __builtin_amdgcn_fmed3f(val, -10.0f, 10.0f);

        // ================= post-u tail =================
        float rd1 = fmaf(B1, u, A1);
        float rd3 = fmaf(B3, u, A3);
        d0 += A0; d2 += A2; d1 += rd1; d3 += rd3;
        float nmm1 = mmf1 + rd1, nmm3 = mmf3 + rd3;

        float v1 = fmaf(vb1, u, va1);
        float v3 = fmaf(vb3, u, va3);
        // P2 rows: {A10=v1v0, A11=v1v1, A21=v1v2, A31=v1v3}
        float lo2 = r2 ? v2 : v0, hi2 = r2 ? v3 : v1;
        float P2 = row_sum_f((fw5 * v1) * (r1 ? hi2 : lo2));
        // P3 rows: {A30=v3v0, A32=v3v2, A33=v3v3, A22=v2v2}  (row3 slot reclaimed)
        float xa = r2 ? (r1 ? v2 : v3) : v3;
        float ya = r1 ? v2 : (r2 ? v3 : v0);
        float P3 = row_sum_f((fw5 * xa) * ya);
        float A10 = rl(P2, 0), A11 = rl(P2, 16) + DIAG5;
        float A21 = rl(P2, 32), A31 = rl(P2, 48);
        float A30 = rl(P3, 0), A32 = rl(P3, 16);
        float A33 = rl(P3, 32) + DIAG5, A22 = rl(P3, 48) + DIAG5;

        // reward (post-step mean & cov) — no feedback, f32 is plenty
        float rwm = fmaf(nmm0, nmm0, fmaf(nmm1, nmm1,
                    fmaf(10.0f * nmm2, nmm2, nmm3 * nmm3)));
        float rwa = A00 + A11 + 10.0f * A22 + A33;
        acc -= fmaf(0.2f, rwa, rwm);

        // remaining cholesky of 5*cov (column 0 partly done pre-u)
        float nc10 = A10 * i0;
        float nc30 = A30 * i0;
        float b11 = fmaf(-nc10, nc10, A11);
        float i1 = __builtin_amdgcn_rsqf(b11);
        float nc11 = b11 * i1;
        float nc21 = fmaf(-nc20, nc10, A21) * i1;
        float nc31 = fmaf(-nc30, nc10, A31) * i1;
        float b22 = fmaf(-nc21, nc21, fmaf(-nc20, nc20, A22));
        float i2 = __builtin_amdgcn_rsqf(b22);
        float nc22 = b22 * i2;
        float nc32 = fmaf(-nc31, nc21, fmaf(-nc30, nc20, A32)) * i2;
        float b33 = fmaf(-nc32, nc32, fmaf(-nc31, nc31, fmaf(-nc30, nc30, A33)));
        float nc33 = b33 * __builtin_amdgcn_rsqf(b33);

        c00 = nc00; c10 = nc10; c20 = nc20; c30 = nc30;
        c11 = nc11; c21 = nc21; c31 = nc31;
        c22 = nc22; c32 = nc32; c33 = nc33;
        mmf0 = nmm0; mmf1 = nmm1; mmf2 = nmm2; mmf3 = nmm3;
        frmf = nfrm;
    }

    if (l == 0) out[0] = acc;
}

extern "C" void kernel_launch(void* const* d_in, const int* in_sizes, int n_in,
                              void* d_out, int out_size, void* d_ws, size_t ws_size,
                              hipStream_t stream) {
    (void)in_sizes; (void)n_in; (void)out_size; (void)d_ws; (void)ws_size;
    const float* p = (const float*)d_in[0];
    float* out = (float*)d_out;
    hipLaunchKernelGGL(horizon_kernel, dim3(1), dim3(64), 0, stream, p, out);
}

// Round 3
// 70.944 us; speedup vs baseline: 1.1701x; 1.0365x over previous
//
#include <hip/hip_runtime.h>
#include <math.h>

// HorizonReward: 60-step UT cartpole rollout, single wave, zero LDS.
//
// v4 = v3 minus ~24 instr/iter (confirmed issue-bound @ ~2.3cy/instr; v2:+150
// instr->+8.6us, v3:-12->-0.9us). Three exact-math instruction deletions:
//  (a) sum_w(offsets) = 0 exactly (+/- columns cancel) =>
//      A0 = DT*mmf1, A2 = DT*mmf3 free, and v0 = fmaf(DT,oo1,oo0),
//      v2 = fmaf(DT,oo3,oo2) DIRECTLY (no x1/dl0/dl2, no centering subs).
//      PB reduces centered {v0v0, v0v2, v2v2} pre-u with NO corrections
//      (center lane's v0=v2=0); +/- points sit in lanes 0..7 so PB is a
//      3-stage 8-lane reduce. PA carries {al1,al3,be1,be3}; P3 loses A22.
//  (b) d_i == mmf_i - mu_i invariantly => policy folds -sum(s*mu) into
//      per-lane init constants; the 4 d-update adds/iter deleted.
//  (c) policy quadratic in packed f32 (v_pk_fma_f32): coefficient pairs
//      packed at init, mm splats broadcast via op_sel; 4 chains -> 2.
// Lane roles: l15 0..3 = +cols, 4..7 = -cols, 8 = center, 9..15 dead.
// Dynamics / f64 angle accumulator / Cholesky unchanged from v3.

typedef float v2f __attribute__((ext_vector_type(2)));

template <int CTRL>
__device__ __forceinline__ float dpp_add_f(float v) {
    int s = __builtin_amdgcn_update_dpp(0, __float_as_int(v), CTRL, 0xF, 0xF, true);
    return v + __int_as_float(s);
}
// sum within each 16-lane row: quad_perm[1,0,3,2], quad_perm[2,3,0,1],
// row_ror:4, row_ror:8
__device__ __forceinline__ float row_sum_f(float v) {
    v = dpp_add_f<0xB1>(v);
    v = dpp_add_f<0x4E>(v);
    v = dpp_add_f<0x124>(v);
    v = dpp_add_f<0x128>(v);
    return v;
}
// sum within each 8-lane half-row: quad_perm x2 + row_half_mirror
__device__ __forceinline__ float row_sum8_f(float v) {
    v = dpp_add_f<0xB1>(v);
    v = dpp_add_f<0x4E>(v);
    v = dpp_add_f<0x141>(v);
    return v;
}
__device__ __forceinline__ float rl(float v, int lane) {
    return __int_as_float(__builtin_amdgcn_readlane(__float_as_int(v), lane));
}
// full 64-lane sum -> lane63, via row_bcast15 / row_bcast31
__device__ __forceinline__ float wave_sum_f(float v) {
    v = row_sum_f(v);
    v = dpp_add_f<0x142>(v);
    v = dpp_add_f<0x143>(v);
    return rl(v, 63);
}

__global__ __launch_bounds__(64) void horizon_kernel(const float* __restrict__ p,
                                                     float* __restrict__ out) {
    const int l   = threadIdx.x;
    const int l15 = l & 15;
    const bool r1 = (l >> 4) & 1, r2 = (l >> 4) & 2;   // row bits
    const bool rbOr = r1 || r2;

    const float SQL2E  = 1.2011224087864498f;   // sqrt(log2 e)
    const float INV_MT = 0.9090909090909091f;   // 1/1.1
    const float KCS    = -0.045454545454545456f;// -0.05/1.1
    const double INV2PI_D = 0.15915494309189535;
    const float  INV2PI_F = 0.15915494309189535f;
    const float DIAG5  = 0.00251f;              // 5*(PN*DT + 2*JITTER)

    // per-lane RBF params, s pre-scaled so exp(-qn) = exp2(-(qn*log2e))
    float w = 0.0f, mu0 = 0.0f, mu1 = 0.0f, mu2 = 0.0f, mu3 = 0.0f;
    float s0=0,s1=0,s2=0,s3=0,s4=0,s5=0,s6=0,s7=0,s8=0,s9=0;
    if (l < 50) {
        w   = p[l];
        mu0 = p[ 50 + l]; mu1 = p[100 + l]; mu2 = p[150 + l]; mu3 = p[200 + l];
        const float* q = p + 250 + 10 * l;
        s0 = q[0]*SQL2E; s1 = q[1]*SQL2E; s2 = q[2]*SQL2E; s3 = q[3]*SQL2E;
        s4 = q[4]*SQL2E; s5 = q[5]*SQL2E; s6 = q[6]*SQL2E; s7 = q[7]*SQL2E;
        s8 = q[8]*SQL2E; s9 = q[9]*SQL2E;
    }

    // policy as function of mm directly: t = sum_j s_j*mm_j - C  (d = mm - mu)
    const float C0 = s0*mu0 + s4*mu1 + s5*mu2 + s7*mu3;
    const float C1 = s1*mu1 + s6*mu2 + s8*mu3;
    const float C2 = s2*mu2 + s9*mu3;
    const float C3 = s3*mu3;
    const v2f kA0 = {s0, 0.0f};   // mm0 coeffs for (t0,t1)
    const v2f kA1 = {s4, s1};
    const v2f kA2 = {s5, s6};
    const v2f kA3 = {s7, s8};
    const v2f kB2 = {s2, 0.0f};   // mm2 coeffs for (t2,t3)
    const v2f kB3 = {s9, s3};
    const v2f cA  = {-C0, -C1};
    const v2f cB  = {-C2, -C3};

    // sigma-point role: l15 0..3 = +cols, 4..7 = -cols, 8 = center
    const float wlf  = (l15 < 8) ? 0.1f : ((l15 == 8) ? 0.2f : 0.0f);
    const float fw5  = 5.0f * wlf;
    const float osgn = (l15 < 4) ? 1.0f : ((l15 < 8) ? -1.0f : 0.0f);
    const int   ocol = l15 & 3;

    // carried state (all f32 except angle accumulator rev)
    float mmf0 = 0.0f, mmf1 = 0.0f, mmf2 = 0.1f, mmf3 = 0.0f;
    double rev = 0.1 * INV2PI_D;                // theta / 2pi, kept in [0,1)
    float frmf = (float)rev;
    const float CI = 2.2360679774997896e-3f;    // sqrt5 * chol(JITTER*I)
    float c00=CI, c10=0.f, c20=0.f, c30=0.f;
    float c11=CI, c21=0.f, c31=0.f;
    float c22=CI, c32=0.f;
    float c33=CI;
    float acc = 0.0f;

    #pragma unroll 2
    for (int t = 0; t < 60; ++t) {
        // ================= pre-u phase =================
        // sigma offset for this lane (column ocol of sqrt5-scaled chol)
        float oo0 = osgn * ((ocol == 0) ? c00 : 0.0f);
        float oo1 = osgn * ((ocol == 0) ? c10 : ((ocol == 1) ? c11 : 0.0f));
        float oo2 = osgn * ((ocol == 0) ? c20 : ((ocol == 1) ? c21 :
                            ((ocol == 2) ? c22 : 0.0f)));
        float oo3 = osgn * ((ocol == 0) ? c30 : ((ocol == 1) ? c31 :
                            ((ocol == 2) ? c32 : c33)));

        float x3 = mmf3 + oo3;

        // dynamics coefficients (affine in u): thacc=g0+g1u, xacc=h0+h1u
        float rv = __builtin_amdgcn_fractf(fmaf(oo2, INV2PI_F, frmf));
        float sn = __builtin_amdgcn_sinf(rv);
        float cs = __builtin_amdgcn_cosf(rv);
        float a   = (0.045454545454545456f * (x3 * x3)) * sn;  // temp - u/MT
        float den = fmaf(cs * cs, KCS, 0.6666666666666666f);
        float rden = __builtin_amdgcn_rcpf(den);
        float g0 = fmaf(9.8f, sn, -(cs * a)) * rden;
        float g1 = (-INV_MT) * (cs * rden);
        float kcs = KCS * cs;
        float h0 = fmaf(kcs, g0, a);
        float h1 = fmaf(kcs, g1, INV_MT);
        float al1 = fmaf(0.05f, h0, oo1), be1 = 0.05f * h1;   // dl1 = al1+be1*u
        float al3 = fmaf(0.05f, g0, oo3), be3 = 0.05f * g1;   // dl3 = al3+be3*u

        // centered u-free deviations, EXACT (sum_w oo = 0): no means needed
        float v0 = fmaf(0.05f, oo1, oo0);
        float v2 = fmaf(0.05f, oo3, oo2);
        float A2 = 0.05f * mmf3;                 // mean delta comp 2 (closed form)

        // PA rows reduce w*{al1, al3, be1, be3} -> A1, A3, B1, B3
        float selA = r2 ? (r1 ? be3 : be1) : (r1 ? al3 : al1);
        float PA = row_sum_f(wlf * selA);
        // PB rows (8-lane, +/- points only; center v0=v2=0):
        // {5w*v0*v0, 5w*v0*v2, 5w*v2*v2} -> A00-D, A20, A22-D directly
        float q0 = fw5 * v0, q2 = fw5 * v2;
        float xb = r2 ? q2 : q0;
        float yb = rbOr ? v2 : v0;
        float PB = row_sum8_f(xb * yb);

        float A1 = rl(PA, 0), A3 = rl(PA, 16), B1 = rl(PA, 32), B3 = rl(PA, 48);
        float A00 = rl(PB, 0) + DIAG5, A20 = rl(PB, 16), A22 = rl(PB, 32) + DIAG5;

        float i0 = __builtin_amdgcn_rsqf(A00);
        float nc00 = A00 * i0;
        float nc20 = A20 * i0;
        float b22p = fmaf(-nc20, nc20, A22);

        // u-free centered pieces for components 1,3
        float va1 = al1 - A1, vb1 = be1 - B1;
        float va3 = al3 - A3, vb3 = be3 - B3;

        // mean components 0,2 update pre-u (closed form)
        float nmm0 = fmaf(0.05f, mmf1, mmf0), nmm2 = fmaf(0.05f, mmf3, mmf2);
        double revn = fma((double)A2, INV2PI_D, rev);
        rev = revn - floor(revn);
        float nfrm = (float)rev;

        // ================= policy (packed f32, on current mm) =================
        v2f mS;
        mS = (v2f){mmf3, mmf3};
        v2f pt  = __builtin_elementwise_fma(kA3, mS, cA);
        v2f pt2 = __builtin_elementwise_fma(kB3, mS, cB);
        mS = (v2f){mmf2, mmf2};
        pt  = __builtin_elementwise_fma(kA2, mS, pt);
        pt2 = __builtin_elementwise_fma(kB2, mS, pt2);
        mS = (v2f){mmf1, mmf1};
        pt  = __builtin_elementwise_fma(kA1, mS, pt);
        mS = (v2f){mmf0, mmf0};
        pt  = __builtin_elementwise_fma(kA0, mS, pt);
        v2f pq = pt * pt;
        pq = __builtin_elementwise_fma(pt2, pt2, pq);
        float qn = pq.x + pq.y;
        float val = wave_sum_f(w * __builtin_amdgcn_exp2f(-qn));
        float u = __builtin_amdgcn_fmed3f(val, -10.0f, 10.0f);

        // ================= post-u tail =================
        float rd1 = fmaf(B1, u, A1);
        float rd3 = fmaf(B3, u, A3);
        float nmm1 = mmf1 + rd1, nmm3 = mmf3 + rd3;

        float v1 = fmaf(vb1, u, va1);
        float v3 = fmaf(vb3, u, va3);
        // P2 rows: {A10=v1v0, A11=v1v1, A21=v1v2, A31=v1v3}
        float lo2 = r2 ? v2 : v0, hi2 = r2 ? v3 : v1;
        float P2 = row_sum_f((fw5 * v1) * (r1 ? hi2 : lo2));
        // P3 rows: {A30=v3v0, A32=v3v2, A33=v3v3, dup}
        float yw = r2 ? v3 : (r1 ? v2 : v0);
        float P3 = row_sum_f((fw5 * v3) * yw);
        float A10 = rl(P2, 0), A11 = rl(P2, 16) + DIAG5;
        float A21 = rl(P2, 32), A31 = rl(P2, 48);
        float A30 = rl(P3, 0), A32 = rl(P3, 16), A33 = rl(P3, 32) + DIAG5;

        // reward (post-step mean & cov) — no feedback, f32 is plenty
        float rwm = fmaf(nmm0, nmm0, fmaf(nmm1, nmm1,
                    fmaf(10.0f * nmm2, nmm2, nmm3 * nmm3)));
        float rwa = A00 + A11 + 10.0f * A22 + A33;
        acc -= fmaf(0.2f, rwa, rwm);

        // remaining cholesky of 5*cov (column 0 partly done pre-u)
        float nc10 = A10 * i0;
        float nc30 = A30 * i0;
        float b11 = fmaf(-nc10, nc10, A11);
        float i1 = __builtin_amdgcn_rsqf(b11);
        float nc11 = b11 * i1;
        float nc21 = fmaf(-nc20, nc10, A21) * i1;
        float nc31 = fmaf(-nc30, nc10, A31) * i1;
        float b22 = fmaf(-nc21, nc21, b22p);
        float i2 = __builtin_amdgcn_rsqf(b22);
        float nc22 = b22 * i2;
        float nc32 = fmaf(-nc31, nc21, fmaf(-nc30, nc20, A32)) * i2;
        float b33 = fmaf(-nc32, nc32, fmaf(-nc31, nc31, fmaf(-nc30, nc30, A33)));
        float nc33 = b33 * __builtin_amdgcn_rsqf(b33);

        c00 = nc00; c10 = nc10; c20 = nc20; c30 = nc30;
        c11 = nc11; c21 = nc21; c31 = nc31;
        c22 = nc22; c32 = nc32; c33 = nc33;
        mmf0 = nmm0; mmf1 = nmm1; mmf2 = nmm2; mmf3 = nmm3;
        frmf = nfrm;
    }

    if (l == 0) out[0] = acc;
}

extern "C" void kernel_launch(void* const* d_in, const int* in_sizes, int n_in,
                              void* d_out, int out_size, void* d_ws, size_t ws_size,
                              hipStream_t stream) {
    (void)in_sizes; (void)n_in; (void)out_size; (void)d_ws; (void)ws_size;
    const float* p = (const float*)d_in[0];
    float* out = (float*)d_out;
    hipLaunchKernelGGL(horizon_kernel, dim3(1), dim3(64), 0, stream, p, out);
}

// Round 5
// 70.260 us; speedup vs baseline: 1.1815x; 1.0097x over previous
//
#include <hip/hip_runtime.h>
#include <math.h>

// HorizonReward: 60-step UT cartpole rollout, single wave, zero LDS.
//
// v5b = v5 resubmission (R4 bench was an infra failure, no signal) with the
// one semantics-risky edit reverted: fract before v_sin/v_cos is RESTORED
// (ISA note says reduce to [0,1) with v_fract first; +1 instr is cheap
// insurance). Remaining v5 deltas vs proven v4 (70.9us), all few-ULP-safe:
//  (1) exact identity h1 = (2/3)*INV_MT*rden (KCS*cs^2 = den - 2/3) =>
//      be1 = K_BE1*rden, be3 = K_BE3*(cs*rden); g1,h1 deleted.
//  (2) f64 angle accumulator -> f32 Kahan (fma/add/sub/sub/fract): residual
//      ~1e-10/step (f64-quality), deletes half-rate f64 ops + cvts + A2.
//  (4) PB first factor: fw5*(r2?v2:v0) (one mul instead of two).
//  (5) unroll 4 (loop overhead halved, more cross-iter scheduling).
// Model: issue-bound @ ~2.3cy/instr (v2:+150instr->+8.6us, v3:-12->-0.9,
// v4:~-45->-2.6). Only instruction deletions pay; chain cuts don't.

typedef float v2f __attribute__((ext_vector_type(2)));

template <int CTRL>
__device__ __forceinline__ float dpp_add_f(float v) {
    int s = __builtin_amdgcn_update_dpp(0, __float_as_int(v), CTRL, 0xF, 0xF, true);
    return v + __int_as_float(s);
}
// sum within each 16-lane row: quad_perm[1,0,3,2], quad_perm[2,3,0,1],
// row_ror:4, row_ror:8
__device__ __forceinline__ float row_sum_f(float v) {
    v = dpp_add_f<0xB1>(v);
    v = dpp_add_f<0x4E>(v);
    v = dpp_add_f<0x124>(v);
    v = dpp_add_f<0x128>(v);
    return v;
}
// sum within each 8-lane half-row: quad_perm x2 + row_half_mirror
__device__ __forceinline__ float row_sum8_f(float v) {
    v = dpp_add_f<0xB1>(v);
    v = dpp_add_f<0x4E>(v);
    v = dpp_add_f<0x141>(v);
    return v;
}
__device__ __forceinline__ float rl(float v, int lane) {
    return __int_as_float(__builtin_amdgcn_readlane(__float_as_int(v), lane));
}
// full 64-lane sum -> lane63, via row_bcast15 / row_bcast31
__device__ __forceinline__ float wave_sum_f(float v) {
    v = row_sum_f(v);
    v = dpp_add_f<0x142>(v);
    v = dpp_add_f<0x143>(v);
    return rl(v, 63);
}

__global__ __launch_bounds__(64) void horizon_kernel(const float* __restrict__ p,
                                                     float* __restrict__ out) {
    const int l   = threadIdx.x;
    const int l15 = l & 15;
    const bool r1 = (l >> 4) & 1, r2 = (l >> 4) & 2;   // row bits
    const bool rbOr = r1 || r2;

    const float SQL2E  = 1.2011224087864498f;   // sqrt(log2 e)
    const float INV_MT = 0.9090909090909091f;   // 1/1.1
    const float KCS    = -0.045454545454545456f;// -0.05/1.1
    const float INV2PI_F = 0.15915494309189535f;
    const float DT_I2P_F = 0.007957747154594767f; // 0.05/(2*pi)
    const float K_BE1  = 0.030303030303030304f; // 0.05*(2/3)*INV_MT
    const float K_BE3  = -0.045454545454545456f;// 0.05*(-INV_MT) folded w/ csrden
    const float DIAG5  = 0.00251f;              // 5*(PN*DT + 2*JITTER)

    // per-lane RBF params, s pre-scaled so exp(-qn) = exp2(-(qn*log2e))
    float w = 0.0f, mu0 = 0.0f, mu1 = 0.0f, mu2 = 0.0f, mu3 = 0.0f;
    float s0=0,s1=0,s2=0,s3=0,s4=0,s5=0,s6=0,s7=0,s8=0,s9=0;
    if (l < 50) {
        w   = p[l];
        mu0 = p[ 50 + l]; mu1 = p[100 + l]; mu2 = p[150 + l]; mu3 = p[200 + l];
        const float* q = p + 250 + 10 * l;
        s0 = q[0]*SQL2E; s1 = q[1]*SQL2E; s2 = q[2]*SQL2E; s3 = q[3]*SQL2E;
        s4 = q[4]*SQL2E; s5 = q[5]*SQL2E; s6 = q[6]*SQL2E; s7 = q[7]*SQL2E;
        s8 = q[8]*SQL2E; s9 = q[9]*SQL2E;
    }

    // policy as function of mm directly: t = sum_j s_j*mm_j - C  (d = mm - mu)
    const float C0 = s0*mu0 + s4*mu1 + s5*mu2 + s7*mu3;
    const float C1 = s1*mu1 + s6*mu2 + s8*mu3;
    const float C2 = s2*mu2 + s9*mu3;
    const float C3 = s3*mu3;
    const v2f kA0 = {s0, 0.0f};   // mm0 coeffs for (t0,t1)
    const v2f kA1 = {s4, s1};
    const v2f kA2 = {s5, s6};
    const v2f kA3 = {s7, s8};
    const v2f kB2 = {s2, 0.0f};   // mm2 coeffs for (t2,t3)
    const v2f kB3 = {s9, s3};
    const v2f cA  = {-C0, -C1};
    const v2f cB  = {-C2, -C3};

    // sigma-point role: l15 0..3 = +cols, 4..7 = -cols, 8 = center
    const float wlf  = (l15 < 8) ? 0.1f : ((l15 == 8) ? 0.2f : 0.0f);
    const float fw5  = 5.0f * wlf;
    const float osgn = (l15 < 4) ? 1.0f : ((l15 < 8) ? -1.0f : 0.0f);
    const int   ocol = l15 & 3;

    // carried state (all f32; angle tracked as Kahan-compensated revolutions)
    float mmf0 = 0.0f, mmf1 = 0.0f, mmf2 = 0.1f, mmf3 = 0.0f;
    float frmf = 0.1f * INV2PI_F;               // theta/2pi in [0,1)
    float comp = 0.0f;                          // Kahan compensation
    const float CI = 2.2360679774997896e-3f;    // sqrt5 * chol(JITTER*I)
    float c00=CI, c10=0.f, c20=0.f, c30=0.f;
    float c11=CI, c21=0.f, c31=0.f;
    float c22=CI, c32=0.f;
    float c33=CI;
    float acc = 0.0f;

    #pragma unroll 4
    for (int t = 0; t < 60; ++t) {
        // ================= pre-u phase =================
        // sigma offset for this lane (column ocol of sqrt5-scaled chol)
        float oo0 = osgn * ((ocol == 0) ? c00 : 0.0f);
        float oo1 = osgn * ((ocol == 0) ? c10 : ((ocol == 1) ? c11 : 0.0f));
        float oo2 = osgn * ((ocol == 0) ? c20 : ((ocol == 1) ? c21 :
                            ((ocol == 2) ? c22 : 0.0f)));
        float oo3 = osgn * ((ocol == 0) ? c30 : ((ocol == 1) ? c31 :
                            ((ocol == 2) ? c32 : c33)));

        float x3 = mmf3 + oo3;

        // dynamics coefficients (affine in u): thacc=g0+g1u, xacc=h0+h1u
        float rv = __builtin_amdgcn_fractf(fmaf(oo2, INV2PI_F, frmf));
        float sn = __builtin_amdgcn_sinf(rv);
        float cs = __builtin_amdgcn_cosf(rv);
        float a   = (0.045454545454545456f * (x3 * x3)) * sn;  // temp - u/MT
        float den = fmaf(cs * cs, KCS, 0.6666666666666666f);
        float rden = __builtin_amdgcn_rcpf(den);
        float csrden = cs * rden;
        float g0 = fmaf(9.8f, sn, -(cs * a)) * rden;
        float kcs = KCS * cs;
        float h0 = fmaf(kcs, g0, a);
        float al1 = fmaf(0.05f, h0, oo1);
        float be1 = K_BE1 * rden;      // 0.05*h1; h1 == (2/3)*INV_MT*rden exact
        float al3 = fmaf(0.05f, g0, oo3);
        float be3 = K_BE3 * csrden;    // 0.05*g1

        // centered u-free deviations, EXACT (sum_w oo = 0): no means needed
        float v0 = fmaf(0.05f, oo1, oo0);
        float v2 = fmaf(0.05f, oo3, oo2);

        // PA rows reduce w*{al1, al3, be1, be3} -> A1, A3, B1, B3
        float selA = r2 ? (r1 ? be3 : be1) : (r1 ? al3 : al1);
        float PA = row_sum_f(wlf * selA);
        // PB rows (8-lane, +/- points only; center v0=v2=0):
        // {5w*v0*v0, 5w*v0*v2, 5w*v2*v2} -> A00-D, A20, A22-D directly
        float xb = fw5 * (r2 ? v2 : v0);
        float yb = rbOr ? v2 : v0;
        float PB = row_sum8_f(xb * yb);

        float A1 = rl(PA, 0), A3 = rl(PA, 16), B1 = rl(PA, 32), B3 = rl(PA, 48);
        float A00 = rl(PB, 0) + DIAG5, A20 = rl(PB, 16), A22 = rl(PB, 32) + DIAG5;

        float i0 = __builtin_amdgcn_rsqf(A00);
        float nc00 = A00 * i0;
        float nc20 = A20 * i0;
        float b22p = fmaf(-nc20, nc20, A22);

        // u-free centered pieces for components 1,3
        float va1 = al1 - A1, vb1 = be1 - B1;
        float va3 = al3 - A3, vb3 = be3 - B3;

        // mean components 0,2 update pre-u (closed form)
        float nmm0 = fmaf(0.05f, mmf1, mmf0), nmm2 = fmaf(0.05f, mmf3, mmf2);
        // angle accumulator: Kahan-compensated f32 revolutions
        float ky = fmaf(mmf3, DT_I2P_F, comp);
        float kt = frmf + ky;
        comp = ky - (kt - frmf);
        float nfrm = __builtin_amdgcn_fractf(kt);

        // ================= policy (packed f32, on current mm) =================
        v2f mS;
        mS = (v2f){mmf3, mmf3};
        v2f pt  = __builtin_elementwise_fma(kA3, mS, cA);
        v2f pt2 = __builtin_elementwise_fma(kB3, mS, cB);
        mS = (v2f){mmf2, mmf2};
        pt  = __builtin_elementwise_fma(kA2, mS, pt);
        pt2 = __builtin_elementwise_fma(kB2, mS, pt2);
        mS = (v2f){mmf1, mmf1};
        pt  = __builtin_elementwise_fma(kA1, mS, pt);
        mS = (v2f){mmf0, mmf0};
        pt  = __builtin_elementwise_fma(kA0, mS, pt);
        v2f pq = pt * pt;
        pq = __builtin_elementwise_fma(pt2, pt2, pq);
        float qn = pq.x + pq.y;
        float val = wave_sum_f(w * __builtin_amdgcn_exp2f(-qn));
        float u = __builtin_amdgcn_fmed3f(val, -10.0f, 10.0f);

        // ================= post-u tail =================
        float rd1 = fmaf(B1, u, A1);
        float rd3 = fmaf(B3, u, A3);
        float nmm1 = mmf1 + rd1, nmm3 = mmf3 + rd3;

        float v1 = fmaf(vb1, u, va1);
        float v3 = fmaf(vb3, u, va3);
        // P2 rows: {A10=v1v0, A11=v1v1, A21=v1v2, A31=v1v3}
        float lo2 = r2 ? v2 : v0, hi2 = r2 ? v3 : v1;
        float P2 = row_sum_f((fw5 * v1) * (r1 ? hi2 : lo2));
        // P3 rows: {A30=v3v0, A32=v3v2, A33=v3v3, dup}
        float yw = r2 ? v3 : (r1 ? v2 : v0);
        float P3 = row_sum_f((fw5 * v3) * yw);
        float A10 = rl(P2, 0), A11 = rl(P2, 16) + DIAG5;
        float A21 = rl(P2, 32), A31 = rl(P2, 48);
        float A30 = rl(P3, 0), A32 = rl(P3, 16), A33 = rl(P3, 32) + DIAG5;

        // reward (post-step mean & cov) — no feedback, f32 is plenty
        float rwm = fmaf(nmm0, nmm0, fmaf(nmm1, nmm1,
                    fmaf(10.0f * nmm2, nmm2, nmm3 * nmm3)));
        float rwa = A00 + A11 + 10.0f * A22 + A33;
        acc -= fmaf(0.2f, rwa, rwm);

        // remaining cholesky of 5*cov (column 0 partly done pre-u)
        float nc10 = A10 * i0;
        float nc30 = A30 * i0;
        float b11 = fmaf(-nc10, nc10, A11);
        float i1 = __builtin_amdgcn_rsqf(b11);
        float nc11 = b11 * i1;
        float nc21 = fmaf(-nc20, nc10, A21) * i1;
        float nc31 = fmaf(-nc30, nc10, A31) * i1;
        float b22 = fmaf(-nc21, nc21, b22p);
        float i2 = __builtin_amdgcn_rsqf(b22);
        float nc22 = b22 * i2;
        float nc32 = fmaf(-nc31, nc21, fmaf(-nc30, nc20, A32)) * i2;
        float b33 = fmaf(-nc32, nc32, fmaf(-nc31, nc31, fmaf(-nc30, nc30, A33)));
        float nc33 = b33 * __builtin_amdgcn_rsqf(b33);

        c00 = nc00; c10 = nc10; c20 = nc20; c30 = nc30;
        c11 = nc11; c21 = nc21; c31 = nc31;
        c22 = nc22; c32 = nc32; c33 = nc33;
        mmf0 = nmm0; mmf1 = nmm1; mmf2 = nmm2; mmf3 = nmm3;
        frmf = nfrm;
    }

    if (l == 0) out[0] = acc;
}

extern "C" void kernel_launch(void* const* d_in, const int* in_sizes, int n_in,
                              void* d_out, int out_size, void* d_ws, size_t ws_size,
                              hipStream_t stream) {
    (void)in_sizes; (void)n_in; (void)out_size; (void)d_ws; (void)ws_size;
    const float* p = (const float*)d_in[0];
    float* out = (float*)d_out;
    hipLaunchKernelGGL(horizon_kernel, dim3(1), dim3(64), 0, stream, p, out);
}

// Round 6
// 69.988 us; speedup vs baseline: 1.1861x; 1.0039x over previous
//
#include <hip/hip_runtime.h>
#include <math.h>

// HorizonReward: 60-step UT cartpole rollout, single wave, zero LDS.
//
// v6 = v5b (70.26us) minus 8 instr/iter, both bit-identical rewrites.
// Model (4 matched predictions): issue-bound @ ~2.3cy/instr; kernel ~8.7us
// + ~61.5us fixed harness overhead. Only static-count deletions pay.
//  (1) sigma offsets via per-lane SIGNED masks sm_j = (ocol==j)?osgn:0:
//      oo_j = chained fma of sm*c — 10 ops vs 13 (cndmask chains + osgn
//      muls). Exact: every fma has a zero operand or pure sign product.
//  (2) post-u P2/P3 -> Q1/Q2 with SHARED first factor g = fw5*(r2?v3:v1):
//      Q1 (16-lane, 4-stage) rows {A11, A31, A33, dup} — the center
//      contributes to these; Q2 (8-lane lower halves, 3-stage) rows
//      {A10, A21, A30, A32} — center's v0=v2=0 kills them exactly.
//      12 ops vs 17. Bit-identical (old rounds' upper halves were exact 0).
// Kept: fract before v_sin/v_cos (ISA: reduce first), f32 Kahan angle
// accumulator, packed-f32 policy, pre-u PA||PB single round, closed-form
// mean components 0/2, Cholesky structure.

typedef float v2f __attribute__((ext_vector_type(2)));

template <int CTRL>
__device__ __forceinline__ float dpp_add_f(float v) {
    int s = __builtin_amdgcn_update_dpp(0, __float_as_int(v), CTRL, 0xF, 0xF, true);
    return v + __int_as_float(s);
}
// sum within each 16-lane row: quad_perm[1,0,3,2], quad_perm[2,3,0,1],
// row_ror:4, row_ror:8
__device__ __forceinline__ float row_sum_f(float v) {
    v = dpp_add_f<0xB1>(v);
    v = dpp_add_f<0x4E>(v);
    v = dpp_add_f<0x124>(v);
    v = dpp_add_f<0x128>(v);
    return v;
}
// sum within each 8-lane half-row: quad_perm x2 + row_half_mirror
__device__ __forceinline__ float row_sum8_f(float v) {
    v = dpp_add_f<0xB1>(v);
    v = dpp_add_f<0x4E>(v);
    v = dpp_add_f<0x141>(v);
    return v;
}
__device__ __forceinline__ float rl(float v, int lane) {
    return __int_as_float(__builtin_amdgcn_readlane(__float_as_int(v), lane));
}
// full 64-lane sum -> lane63, via row_bcast15 / row_bcast31
__device__ __forceinline__ float wave_sum_f(float v) {
    v = row_sum_f(v);
    v = dpp_add_f<0x142>(v);
    v = dpp_add_f<0x143>(v);
    return rl(v, 63);
}

__global__ __launch_bounds__(64) void horizon_kernel(const float* __restrict__ p,
                                                     float* __restrict__ out) {
    const int l   = threadIdx.x;
    const int l15 = l & 15;
    const bool r1 = (l >> 4) & 1, r2 = (l >> 4) & 2;   // row bits
    const bool rbOr = r1 || r2;

    const float SQL2E  = 1.2011224087864498f;   // sqrt(log2 e)
    const float INV_MT = 0.9090909090909091f;   // 1/1.1
    const float KCS    = -0.045454545454545456f;// -0.05/1.1
    const float INV2PI_F = 0.15915494309189535f;
    const float DT_I2P_F = 0.007957747154594767f; // 0.05/(2*pi)
    const float K_BE1  = 0.030303030303030304f; // 0.05*(2/3)*INV_MT
    const float K_BE3  = -0.045454545454545456f;// 0.05*(-INV_MT) folded w/ csrden
    const float DIAG5  = 0.00251f;              // 5*(PN*DT + 2*JITTER)

    // per-lane RBF params, s pre-scaled so exp(-qn) = exp2(-(qn*log2e))
    float w = 0.0f, mu0 = 0.0f, mu1 = 0.0f, mu2 = 0.0f, mu3 = 0.0f;
    float s0=0,s1=0,s2=0,s3=0,s4=0,s5=0,s6=0,s7=0,s8=0,s9=0;
    if (l < 50) {
        w   = p[l];
        mu0 = p[ 50 + l]; mu1 = p[100 + l]; mu2 = p[150 + l]; mu3 = p[200 + l];
        const float* q = p + 250 + 10 * l;
        s0 = q[0]*SQL2E; s1 = q[1]*SQL2E; s2 = q[2]*SQL2E; s3 = q[3]*SQL2E;
        s4 = q[4]*SQL2E; s5 = q[5]*SQL2E; s6 = q[6]*SQL2E; s7 = q[7]*SQL2E;
        s8 = q[8]*SQL2E; s9 = q[9]*SQL2E;
    }

    // policy as function of mm directly: t = sum_j s_j*mm_j - C  (d = mm - mu)
    const float C0 = s0*mu0 + s4*mu1 + s5*mu2 + s7*mu3;
    const float C1 = s1*mu1 + s6*mu2 + s8*mu3;
    const float C2 = s2*mu2 + s9*mu3;
    const float C3 = s3*mu3;
    const v2f kA0 = {s0, 0.0f};   // mm0 coeffs for (t0,t1)
    const v2f kA1 = {s4, s1};
    const v2f kA2 = {s5, s6};
    const v2f kA3 = {s7, s8};
    const v2f kB2 = {s2, 0.0f};   // mm2 coeffs for (t2,t3)
    const v2f kB3 = {s9, s3};
    const v2f cA  = {-C0, -C1};
    const v2f cB  = {-C2, -C3};

    // sigma-point role: l15 0..3 = +cols, 4..7 = -cols, 8 = center
    const float wlf  = (l15 < 8) ? 0.1f : ((l15 == 8) ? 0.2f : 0.0f);
    const float fw5  = 5.0f * wlf;
    const float osgn = (l15 < 4) ? 1.0f : ((l15 < 8) ? -1.0f : 0.0f);
    const int   ocol = l15 & 3;
    // signed column-indicator masks (invariant): sm_j = (ocol==j) ? osgn : 0
    const float sm0 = (ocol == 0) ? osgn : 0.0f;
    const float sm1 = (ocol == 1) ? osgn : 0.0f;
    const float sm2 = (ocol == 2) ? osgn : 0.0f;
    const float sm3 = (ocol == 3) ? osgn : 0.0f;

    // carried state (all f32; angle tracked as Kahan-compensated revolutions)
    float mmf0 = 0.0f, mmf1 = 0.0f, mmf2 = 0.1f, mmf3 = 0.0f;
    float frmf = 0.1f * INV2PI_F;               // theta/2pi in [0,1)
    float comp = 0.0f;                          // Kahan compensation
    const float CI = 2.2360679774997896e-3f;    // sqrt5 * chol(JITTER*I)
    float c00=CI, c10=0.f, c20=0.f, c30=0.f;
    float c11=CI, c21=0.f, c31=0.f;
    float c22=CI, c32=0.f;
    float c33=CI;
    float acc = 0.0f;

    #pragma unroll 4
    for (int t = 0; t < 60; ++t) {
        // ================= pre-u phase =================
        // sigma offset: column ocol of sqrt5-scaled chol, sign baked in sm_j
        float oo0 = sm0 * c00;
        float oo1 = fmaf(sm1, c11, sm0 * c10);
        float oo2 = fmaf(sm2, c22, fmaf(sm1, c21, sm0 * c20));
        float oo3 = fmaf(sm3, c33, fmaf(sm2, c32, fmaf(sm1, c31, sm0 * c30)));

        float x3 = mmf3 + oo3;

        // dynamics coefficients (affine in u): thacc=g0+g1u, xacc=h0+h1u
        float rv = __builtin_amdgcn_fractf(fmaf(oo2, INV2PI_F, frmf));
        float sn = __builtin_amdgcn_sinf(rv);
        float cs = __builtin_amdgcn_cosf(rv);
        float a   = (0.045454545454545456f * (x3 * x3)) * sn;  // temp - u/MT
        float den = fmaf(cs * cs, KCS, 0.6666666666666666f);
        float rden = __builtin_amdgcn_rcpf(den);
        float csrden = cs * rden;
        float g0 = fmaf(9.8f, sn, -(cs * a)) * rden;
        float kcs = KCS * cs;
        float h0 = fmaf(kcs, g0, a);
        float al1 = fmaf(0.05f, h0, oo1);
        float be1 = K_BE1 * rden;      // 0.05*h1; h1 == (2/3)*INV_MT*rden exact
        float al3 = fmaf(0.05f, g0, oo3);
        float be3 = K_BE3 * csrden;    // 0.05*g1

        // centered u-free deviations, EXACT (sum_w oo = 0): no means needed
        float v0 = fmaf(0.05f, oo1, oo0);
        float v2 = fmaf(0.05f, oo3, oo2);

        // PA rows reduce w*{al1, al3, be1, be3} -> A1, A3, B1, B3
        float selA = r2 ? (r1 ? be3 : be1) : (r1 ? al3 : al1);
        float PA = row_sum_f(wlf * selA);
        // PB rows (8-lane, +/- points only; center v0=v2=0):
        // {5w*v0*v0, 5w*v0*v2, 5w*v2*v2} -> A00-D, A20, A22-D directly
        float xb = fw5 * (r2 ? v2 : v0);
        float yb = rbOr ? v2 : v0;
        float PB = row_sum8_f(xb * yb);

        float A1 = rl(PA, 0), A3 = rl(PA, 16), B1 = rl(PA, 32), B3 = rl(PA, 48);
        float A00 = rl(PB, 0) + DIAG5, A20 = rl(PB, 16), A22 = rl(PB, 32) + DIAG5;

        float i0 = __builtin_amdgcn_rsqf(A00);
        float nc00 = A00 * i0;
        float nc20 = A20 * i0;
        float b22p = fmaf(-nc20, nc20, A22);

        // u-free centered pieces for components 1,3
        float va1 = al1 - A1, vb1 = be1 - B1;
        float va3 = al3 - A3, vb3 = be3 - B3;

        // mean components 0,2 update pre-u (closed form)
        float nmm0 = fmaf(0.05f, mmf1, mmf0), nmm2 = fmaf(0.05f, mmf3, mmf2);
        // angle accumulator: Kahan-compensated f32 revolutions
        float ky = fmaf(mmf3, DT_I2P_F, comp);
        float kt = frmf + ky;
        comp = ky - (kt - frmf);
        float nfrm = __builtin_amdgcn_fractf(kt);

        // ================= policy (packed f32, on current mm) =================
        v2f mS;
        mS = (v2f){mmf3, mmf3};
        v2f pt  = __builtin_elementwise_fma(kA3, mS, cA);
        v2f pt2 = __builtin_elementwise_fma(kB3, mS, cB);
        mS = (v2f){mmf2, mmf2};
        pt  = __builtin_elementwise_fma(kA2, mS, pt);
        pt2 = __builtin_elementwise_fma(kB2, mS, pt2);
        mS = (v2f){mmf1, mmf1};
        pt  = __builtin_elementwise_fma(kA1, mS, pt);
        mS = (v2f){mmf0, mmf0};
        pt  = __builtin_elementwise_fma(kA0, mS, pt);
        v2f pq = pt * pt;
        pq = __builtin_elementwise_fma(pt2, pt2, pq);
        float qn = pq.x + pq.y;
        float val = wave_sum_f(w * __builtin_amdgcn_exp2f(-qn));
        float u = __builtin_amdgcn_fmed3f(val, -10.0f, 10.0f);

        // ================= post-u tail =================
        float rd1 = fmaf(B1, u, A1);
        float rd3 = fmaf(B3, u, A3);
        float nmm1 = mmf1 + rd1, nmm3 = mmf3 + rd3;

        float v1 = fmaf(vb1, u, va1);
        float v3 = fmaf(vb3, u, va3);
        // shared first factor for both post-u rounds: rows {0,1}->v1, {2,3}->v3
        float f1 = r2 ? v3 : v1;
        float g  = fw5 * f1;
        // Q1 (16-lane, center contributes): rows {A11=v1v1, A31=v1v3,
        // A33=v3v3, dup}
        float f2 = rbOr ? v3 : v1;
        float Q1 = row_sum_f(g * f2);
        // Q2 (8-lane lower halves, center exactly dead): rows
        // {A10=v1v0, A21=v1v2, A30=v3v0, A32=v3v2}
        float fB = r1 ? v2 : v0;
        float Q2 = row_sum8_f(g * fB);
        float A11 = rl(Q1, 0) + DIAG5, A31 = rl(Q1, 16), A33 = rl(Q1, 32) + DIAG5;
        float A10 = rl(Q2, 0), A21 = rl(Q2, 16);
        float A30 = rl(Q2, 32), A32 = rl(Q2, 48);

        // reward (post-step mean & cov) — no feedback, f32 is plenty
        float rwm = fmaf(nmm0, nmm0, fmaf(nmm1, nmm1,
                    fmaf(10.0f * nmm2, nmm2, nmm3 * nmm3)));
        float rwa = A00 + A11 + 10.0f * A22 + A33;
        acc -= fmaf(0.2f, rwa, rwm);

        // remaining cholesky of 5*cov (column 0 partly done pre-u)
        float nc10 = A10 * i0;
        float nc30 = A30 * i0;
        float b11 = fmaf(-nc10, nc10, A11);
        float i1 = __builtin_amdgcn_rsqf(b11);
        float nc11 = b11 * i1;
        float nc21 = fmaf(-nc20, nc10, A21) * i1;
        float nc31 = fmaf(-nc30, nc10, A31) * i1;
        float b22 = fmaf(-nc21, nc21, b22p);
        float i2 = __builtin_amdgcn_rsqf(b22);
        float nc22 = b22 * i2;
        float nc32 = fmaf(-nc31, nc21, fmaf(-nc30, nc20, A32)) * i2;
        float b33 = fmaf(-nc32, nc32, fmaf(-nc31, nc31, fmaf(-nc30, nc30, A33)));
        float nc33 = b33 * __builtin_amdgcn_rsqf(b33);

        c00 = nc00; c10 = nc10; c20 = nc20; c30 = nc30;
        c11 = nc11; c21 = nc21; c31 = nc31;
        c22 = nc22; c32 = nc32; c33 = nc33;
        mmf0 = nmm0; mmf1 = nmm1; mmf2 = nmm2; mmf3 = nmm3;
        frmf = nfrm;
    }

    if (l == 0) out[0] = acc;
}

extern "C" void kernel_launch(void* const* d_in, const int* in_sizes, int n_in,
                              void* d_out, int out_size, void* d_ws, size_t ws_size,
                              hipStream_t stream) {
    (void)in_sizes; (void)n_in; (void)out_size; (void)d_ws; (void)ws_size;
    const float* p = (const float*)d_in[0];
    float* out = (float*)d_out;
    hipLaunchKernelGGL(horizon_kernel, dim3(1), dim3(64), 0, stream, p, out);
}